// Round 3
// baseline (234.449 us; speedup 1.0000x reference)
//
#include <hip/hip_runtime.h>

// SSIM loss, fused, LDS-free, register-streaming. fp32 [16,3,512,512] x2 -> scalar.
// Each thread owns 4 aligned columns x 16 output rows. Horizontal 7-tap from four
// guarded aligned float4 loads (static indexing, no parity selects); vertical
// 7-tap via 7-slot register ring of 5-channel partials, fully unrolled.
// Final mean via one atomicAdd per block: out = sum_b (1/B - s_b/N).

#define IMG 512
#define BAND 16
#define INROWS 22
#define NPLANES 48
#define NBLK ((IMG / BAND) * NPLANES)   // 32*48 = 1536
#define SSIM_C1 1.0e-4f
#define SSIM_C2 9.0e-4f

__device__ __constant__ float c_gw[7] = {
    0.03663284536f, 0.11128076166f, 0.21674531251f, 0.27068216094f,
    0.21674531251f, 0.11128076166f, 0.03663284536f};

__global__ __launch_bounds__(128, 2) void ssim_main(
    const float* __restrict__ X, const float* __restrict__ Y,
    float* __restrict__ out) {
  const int lane = threadIdx.x;           // 0..127
  const int band = blockIdx.x;            // 0..31
  const int plane = blockIdx.y;           // 0..47
  const float* __restrict__ xp = X + (size_t)plane * IMG * IMG;
  const float* __restrict__ yp = Y + (size_t)plane * IMG * IMG;

  const int c = lane * 4;                 // first output col (0..508), 16B aligned
  const int b0 = c - 4;                   // load base col
  const int row0 = band * BAND - 3;

  // Per-float4 validity (all-or-nothing, b0 is a multiple of 4).
  const bool ok0 = (c >= 4);
  const bool ok2 = (c <= 504);
  const bool ok3 = (c <= 500);

  const float g0 = c_gw[0], g1 = c_gw[1], g2 = c_gw[2], g3 = c_gw[3];
  const float gw[7] = {g0, g1, g2, g3, g2, g1, g0};

  float acc[7][20];                       // ring: slot x (ch*4 + px)
  float ssim_acc = 0.f;

#pragma unroll
  for (int ir = 0; ir < INROWS; ++ir) {
    const int gy = row0 + ir;
    const bool rowok = (unsigned)gy < (unsigned)IMG;
    const float* xr = xp + (size_t)gy * IMG + b0;
    const float* yr = yp + (size_t)gy * IMG + b0;

    const float4 z4 = make_float4(0.f, 0.f, 0.f, 0.f);
    float4 x0 = z4, x1 = z4, x2 = z4, x3 = z4;
    float4 y0 = z4, y1 = z4, y2 = z4, y3 = z4;
    if (rowok) {
      if (ok0) x0 = *(const float4*)(xr);
      x1 = *(const float4*)(xr + 4);
      if (ok2) x2 = *(const float4*)(xr + 8);
      if (ok3) x3 = *(const float4*)(xr + 12);
      if (ok0) y0 = *(const float4*)(yr);
      y1 = *(const float4*)(yr + 4);
      if (ok2) y2 = *(const float4*)(yr + 8);
      if (ok3) y3 = *(const float4*)(yr + 12);
    }
    const float wx[16] = {x0.x, x0.y, x0.z, x0.w, x1.x, x1.y, x1.z, x1.w,
                          x2.x, x2.y, x2.z, x2.w, x3.x, x3.y, x3.z, x3.w};
    const float wy[16] = {y0.x, y0.y, y0.z, y0.w, y1.x, y1.y, y1.z, y1.w,
                          y2.x, y2.y, y2.z, y2.w, y3.x, y3.y, y3.z, y3.w};

    // Horizontal 7-tap, 5 channels x 4 px; squares fused (t=g*x; h+=t; hxx+=t*x).
    float h[20];
#pragma unroll
    for (int q = 0; q < 20; ++q) h[q] = 0.f;
#pragma unroll
    for (int k = 0; k < 7; ++k) {
      const float g = gw[k];
#pragma unroll
      for (int p = 0; p < 4; ++p) {
        const float xv = wx[1 + p + k];
        const float yv = wy[1 + p + k];
        const float t1 = g * xv;
        const float t2 = g * yv;
        h[0 * 4 + p] += t1;
        h[1 * 4 + p] += t2;
        h[2 * 4 + p] = __builtin_fmaf(t1, xv, h[2 * 4 + p]);
        h[3 * 4 + p] = __builtin_fmaf(t2, yv, h[3 * 4 + p]);
        h[4 * 4 + p] = __builtin_fmaf(t1, yv, h[4 * 4 + p]);
      }
    }

    // Vertical fold into ring (static after unroll).
#pragma unroll
    for (int d = 0; d < 7; ++d) {
      if (d <= ir && (ir - d) < BAND) {
        const int s = (ir - d) % 7;
        const float g = gw[d];
        if (d == 0) {
#pragma unroll
          for (int q = 0; q < 20; ++q) acc[s][q] = g * h[q];
        } else {
#pragma unroll
          for (int q = 0; q < 20; ++q) acc[s][q] += g * h[q];
        }
      }
    }

    // Emit completed output row (local row ir-6).
    if (ir >= 6) {
      const int s = (ir - 6) % 7;
#pragma unroll
      for (int p = 0; p < 4; ++p) {
        const float mu1 = acc[s][0 * 4 + p];
        const float mu2 = acc[s][1 * 4 + p];
        const float exx = acc[s][2 * 4 + p];
        const float eyy = acc[s][3 * 4 + p];
        const float exy = acc[s][4 * 4 + p];
        const float mu1sq = mu1 * mu1;
        const float mu2sq = mu2 * mu2;
        const float mu12 = mu1 * mu2;
        const float sig1 = exx - mu1sq;
        const float sig2 = eyy - mu2sq;
        const float sig12 = exy - mu12;
        const float num = (2.f * mu12 + SSIM_C1) * (2.f * sig12 + SSIM_C2);
        const float den =
            (mu1sq + mu2sq + SSIM_C1) * (sig1 + sig2 + SSIM_C2);
        ssim_acc += num * __builtin_amdgcn_rcpf(den);
      }
    }
  }

  // Block reduction: wave shuffle tree, then across the 2 waves via LDS.
#pragma unroll
  for (int off = 32; off > 0; off >>= 1)
    ssim_acc += __shfl_down(ssim_acc, off, 64);
  __shared__ float wsum[2];
  if ((lane & 63) == 0) wsum[lane >> 6] = ssim_acc;
  __syncthreads();
  if (lane == 0) {
    const float s = wsum[0] + wsum[1];
    const float inv_n = 1.0f / (48.0f * 512.0f * 512.0f);
    atomicAdd(out, 1.0f / (float)NBLK - s * inv_n);
  }
}

extern "C" void kernel_launch(void* const* d_in, const int* in_sizes, int n_in,
                              void* d_out, int out_size, void* d_ws, size_t ws_size,
                              hipStream_t stream) {
  const float* enhanced = (const float*)d_in[0];
  const float* target = (const float*)d_in[1];
  float* out = (float*)d_out;

  hipMemsetAsync(out, 0, sizeof(float), stream);
  dim3 grid(IMG / BAND, NPLANES);   // 32 x 48 = 1536 blocks, 128 thr each
  ssim_main<<<grid, dim3(128), 0, stream>>>(enhanced, target, out);
}